// Round 1
// baseline (625.705 us; speedup 1.0000x reference)
//
#include <hip/hip_runtime.h>
#include <hip/hip_bf16.h>

typedef __bf16 bf16;
typedef __bf16 v8bf __attribute__((ext_vector_type(8)));
typedef float  v4f  __attribute__((ext_vector_type(4)));

constexpr int NB   = 16;     // batch
constexpr int CIN  = 256;    // channels
constexpr int NPOS = 2304;   // 48*48 spatial positions
constexpr int CHID = 512;    // hidden
constexpr int CQK  = 96;     // qk channels

// ---- workspace layout (bytes) ----
constexpr size_t OFF_WH   = 0;                               // [1024][256] bf16
constexpr size_t OFF_WQK  = OFF_WH   + 1024ull*256*2;        // [192][256] bf16
constexpr size_t OFF_WOUT = OFF_WQK  + 192ull*256*2;         // [256][512] bf16
constexpr size_t OFF_XT   = OFF_WOUT + 256ull*512*2;         // [B][N][256] bf16
constexpr size_t OFF_ZT   = OFF_XT   + (size_t)NB*NPOS*CIN*2;    // [B][N][192] bf16 (q:0..95, k:96..191)
constexpr size_t OFF_VG   = OFF_ZT   + (size_t)NB*NPOS*192*2;    // [B][1024][N] bf16 (v:0..511, gate:512..1023)
constexpr size_t OFF_VT   = OFF_VG   + (size_t)NB*1024*NPOS*2;   // [B][N][512] bf16

// ---------------------------------------------------------------------------
// cast weights f32 -> bf16
__global__ void cast_weights(const float* __restrict__ wh, const float* __restrict__ wqk,
                             const float* __restrict__ wo,
                             bf16* __restrict__ whb, bf16* __restrict__ wqkb, bf16* __restrict__ wob) {
    int i = blockIdx.x * 256 + threadIdx.x;
    if (i < 1024*256) whb[i]  = (bf16)wh[i];
    if (i < 192*256)  wqkb[i] = (bf16)wqk[i];
    if (i < 256*512)  wob[i]  = (bf16)wo[i];
}

// ---------------------------------------------------------------------------
// x [B][256][N] f32  ->  xT [B][N][256] bf16
__global__ void transpose_cast_x(const float* __restrict__ x, bf16* __restrict__ xT) {
    __shared__ float tile[32][33];
    const int b = blockIdx.z, c0 = blockIdx.y * 32, n0 = blockIdx.x * 32;
    const int tx = threadIdx.x, ty = threadIdx.y;
    const float* xb = x + (size_t)b * CIN * NPOS;
    bf16* xTb = xT + (size_t)b * NPOS * CIN;
    #pragma unroll
    for (int r = ty; r < 32; r += 8) tile[r][tx] = xb[(size_t)(c0 + r) * NPOS + n0 + tx];
    __syncthreads();
    #pragma unroll
    for (int r = ty; r < 32; r += 8) xTb[(size_t)(n0 + r) * CIN + c0 + tx] = (bf16)tile[tx][r];
}

// ---------------------------------------------------------------------------
// Generic bf16 GEMM: D[m][n] = sum_k A[m][k] * Bt[n][k]   (both operands k-contig)
// A: [M][K], Bt: [NB][NPOS][K].  128x128 tile, BK=32, 4 waves (2x2 of 64x64).
// MODE 0: silu(D+bias) -> out bf16 [NB][1024][NPOS]      (vg)
// MODE 1: silu(D+bias) -> out bf16 [NB][NPOS][192] (T)   (zT)
// MODE 2: D+bias+resid -> out f32  [NB][256][NPOS]       (final)
template<int MODE>
__global__ __launch_bounds__(256) void gemm_bt(
    const bf16* __restrict__ A, const bf16* __restrict__ Bt,
    const float* __restrict__ bias, void* __restrict__ outp,
    const float* __restrict__ resid, int M, int K)
{
    __shared__ bf16 sA[128][40];   // +8 pad: breaks 8-way bank conflict on b128 reads
    __shared__ bf16 sB[128][40];
    const int b = blockIdx.z, mt = blockIdx.x, nt = blockIdx.y;
    const int tid = threadIdx.x;
    const int wave = tid >> 6, lane = tid & 63, lo = lane & 15, hi = lane >> 4;
    const int wr = wave >> 1, wc = wave & 1;

    const bf16* Ab = A  + (size_t)mt * 128 * K;
    const bf16* Bb = Bt + ((size_t)b * NPOS + (size_t)nt * 128) * K;

    const int r0 = tid >> 2, koff = (tid & 3) * 8;   // chunk tid   -> row r0
    const int r1 = r0 + 64;                          // chunk tid+256
    const int nk = K >> 5;
    const bool a0ok = (mt * 128 + r0) < M;
    const bool a1ok = (mt * 128 + r1) < M;

    v4f acc[4][4];
    #pragma unroll
    for (int i = 0; i < 4; ++i)
        #pragma unroll
        for (int j = 0; j < 4; ++j) acc[i][j] = (v4f){0.f, 0.f, 0.f, 0.f};

    uint4 ra0 = {0,0,0,0}, ra1 = {0,0,0,0}, rb0, rb1;
    if (a0ok) ra0 = *(const uint4*)(Ab + (size_t)r0 * K + koff);
    if (a1ok) ra1 = *(const uint4*)(Ab + (size_t)r1 * K + koff);
    rb0 = *(const uint4*)(Bb + (size_t)r0 * K + koff);
    rb1 = *(const uint4*)(Bb + (size_t)r1 * K + koff);

    for (int kt = 0; kt < nk; ++kt) {
        __syncthreads();
        *(uint4*)&sA[r0][koff] = ra0;
        *(uint4*)&sA[r1][koff] = ra1;
        *(uint4*)&sB[r0][koff] = rb0;
        *(uint4*)&sB[r1][koff] = rb1;
        __syncthreads();
        if (kt + 1 < nk) {               // prefetch next k-tile; latency hides under MFMA
            const int kb = (kt + 1) * 32 + koff;
            if (a0ok) ra0 = *(const uint4*)(Ab + (size_t)r0 * K + kb);
            if (a1ok) ra1 = *(const uint4*)(Ab + (size_t)r1 * K + kb);
            rb0 = *(const uint4*)(Bb + (size_t)r0 * K + kb);
            rb1 = *(const uint4*)(Bb + (size_t)r1 * K + kb);
        }
        v8bf af[4], bfr[4];
        #pragma unroll
        for (int i = 0; i < 4; ++i) af[i]  = *(const v8bf*)&sA[wr * 64 + i * 16 + lo][hi * 8];
        #pragma unroll
        for (int j = 0; j < 4; ++j) bfr[j] = *(const v8bf*)&sB[wc * 64 + j * 16 + lo][hi * 8];
        #pragma unroll
        for (int i = 0; i < 4; ++i)
            #pragma unroll
            for (int j = 0; j < 4; ++j)
                acc[i][j] = __builtin_amdgcn_mfma_f32_16x16x32_bf16(af[i], bfr[j], acc[i][j], 0, 0, 0);
    }

    // epilogue: D row = (lane>>4)*4 + r, col = lane&15  (verified gfx950 mapping)
    #pragma unroll
    for (int i = 0; i < 4; ++i) {
        const int mg0 = mt * 128 + wr * 64 + i * 16 + hi * 4;
        #pragma unroll
        for (int j = 0; j < 4; ++j) {
            const int ng = nt * 128 + wc * 64 + j * 16 + lo;
            #pragma unroll
            for (int r = 0; r < 4; ++r) {
                const int mg = mg0 + r;
                if (mg >= M) continue;
                float v = acc[i][j][r] + bias[mg];
                if (MODE == 0) {
                    v = v / (1.f + __expf(-v));
                    ((bf16*)outp)[((size_t)b * 1024 + mg) * NPOS + ng] = (bf16)v;
                } else if (MODE == 1) {
                    v = v / (1.f + __expf(-v));
                    ((bf16*)outp)[((size_t)b * NPOS + ng) * 192 + mg] = (bf16)v;
                } else {
                    const size_t idx = ((size_t)b * CIN + mg) * NPOS + ng;
                    ((float*)outp)[idx] = v + resid[idx];
                }
            }
        }
    }
}

// ---------------------------------------------------------------------------
// Fused attention: for a 64-wide n-tile, loop m in steps of 32:
//   S[64][32] = relu(qT . k)^2   (one 16x16 subtile per wave, 3 MFMA over QK=96)
//   acc[h][n] += v[h][m-tile] * S^T   (16 MFMA per wave; wave w owns h in [64w,64w+64))
// epilogue: *gate, store transposed VT[B][N][512]
__global__ __launch_bounds__(512) void attn_kernel(
    const bf16* __restrict__ zT,   // [NB][NPOS][192]
    const bf16* __restrict__ vg,   // [NB][1024][NPOS]
    bf16* __restrict__ VT)         // [NB][NPOS][512]
{
    __shared__ bf16 sS[64][40];    // padded rows: 2-way banks on b128 reads
    const int b = blockIdx.y, n0 = blockIdx.x * 64;
    const int tid = threadIdx.x;
    const int wave = tid >> 6, lane = tid & 63, lo = lane & 15, hi = lane >> 4;
    const int is = wave >> 1, js = wave & 1;   // this wave's S subtile
    const int h0 = wave * 64;                  // this wave's v-channel block

    const bf16* zTb = zT + (size_t)b * NPOS * 192;
    const bf16* vb  = vg + (size_t)b * 1024 * NPOS;

    v8bf qf[3];
    {
        const bf16* qp = zTb + (size_t)(n0 + is * 16 + lo) * 192 + hi * 8;
        #pragma unroll
        for (int kk = 0; kk < 3; ++kk) qf[kk] = *(const v8bf*)(qp + kk * 32);
    }

    v4f acc[4][4];
    #pragma unroll
    for (int i = 0; i < 4; ++i)
        #pragma unroll
        for (int j = 0; j < 4; ++j) acc[i][j] = (v4f){0.f, 0.f, 0.f, 0.f};

    for (int mt = 0; mt < NPOS / 32; ++mt) {
        const int m0 = mt * 32;
        // ---- S phase ----
        v4f s = (v4f){0.f, 0.f, 0.f, 0.f};
        const bf16* kp = zTb + (size_t)(m0 + js * 16 + lo) * 192 + 96 + hi * 8;
        #pragma unroll
        for (int kk = 0; kk < 3; ++kk) {
            v8bf kf = *(const v8bf*)(kp + kk * 32);
            s = __builtin_amdgcn_mfma_f32_16x16x32_bf16(qf[kk], kf, s, 0, 0, 0);
        }
        __syncthreads();   // prev PV reads of sS are done
        #pragma unroll
        for (int r = 0; r < 4; ++r) {
            float t = s[r];
            t = t > 0.f ? t * t : 0.f;          // relu^2
            sS[is * 16 + hi * 4 + r][js * 16 + lo] = (bf16)t;
        }
        __syncthreads();
        // ---- PV phase ----
        v8bf av[4], bs[4];
        #pragma unroll
        for (int j = 0; j < 4; ++j) bs[j] = *(const v8bf*)&sS[j * 16 + lo][hi * 8];
        #pragma unroll
        for (int i = 0; i < 4; ++i)
            av[i] = *(const v8bf*)(vb + (size_t)(h0 + i * 16 + lo) * NPOS + m0 + hi * 8);
        #pragma unroll
        for (int i = 0; i < 4; ++i)
            #pragma unroll
            for (int j = 0; j < 4; ++j)
                acc[i][j] = __builtin_amdgcn_mfma_f32_16x16x32_bf16(av[i], bs[j], acc[i][j], 0, 0, 0);
    }

    // epilogue: V = acc * gate, store VT[b][n][h] (4 consecutive h per lane)
    #pragma unroll
    for (int i = 0; i < 4; ++i) {
        #pragma unroll
        for (int r = 0; r < 4; ++r) {
            const int h = h0 + i * 16 + hi * 4 + r;
            const bf16* gp = vb + (size_t)(512 + h) * NPOS + n0;
            #pragma unroll
            for (int j = 0; j < 4; ++j) {
                const int n = n0 + j * 16 + lo;
                const float g = (float)gp[j * 16 + lo];
                VT[((size_t)b * NPOS + n) * CHID + h] = (bf16)(acc[i][j][r] * g);
            }
        }
    }
}

// ---------------------------------------------------------------------------
extern "C" void kernel_launch(void* const* d_in, const int* in_sizes, int n_in,
                              void* d_out, int out_size, void* d_ws, size_t ws_size,
                              hipStream_t stream) {
    const float* x   = (const float*)d_in[0];
    const float* wh  = (const float*)d_in[1];
    const float* bh  = (const float*)d_in[2];
    const float* wqk = (const float*)d_in[3];
    const float* bqk = (const float*)d_in[4];
    const float* wo  = (const float*)d_in[5];
    const float* bo  = (const float*)d_in[6];

    char* ws = (char*)d_ws;
    bf16* whb  = (bf16*)(ws + OFF_WH);
    bf16* wqkb = (bf16*)(ws + OFF_WQK);
    bf16* wob  = (bf16*)(ws + OFF_WOUT);
    bf16* xT   = (bf16*)(ws + OFF_XT);
    bf16* zT   = (bf16*)(ws + OFF_ZT);
    bf16* vg   = (bf16*)(ws + OFF_VG);
    bf16* VT   = (bf16*)(ws + OFF_VT);

    cast_weights<<<1024, 256, 0, stream>>>(wh, wqk, wo, whb, wqkb, wob);
    transpose_cast_x<<<dim3(72, 8, 16), dim3(32, 8), 0, stream>>>(x, xT);
    // hid = silu(Wh x + bh): v rows 0..511, gate rows 512..1023
    gemm_bt<0><<<dim3(8, 18, 16), 256, 0, stream>>>(whb, xT, bh, vg, nullptr, 1024, 256);
    // z = silu(Wqk x + bqk), stored transposed: q cols 0..95, k cols 96..191
    gemm_bt<1><<<dim3(2, 18, 16), 256, 0, stream>>>(wqkb, xT, bqk, zT, nullptr, 192, 256);
    // fused relu^2 attention + gate, stores VT[B][N][512]
    attn_kernel<<<dim3(36, 16), 512, 0, stream>>>(zT, vg, VT);
    // out = Wout V + bo + x
    gemm_bt<2><<<dim3(2, 18, 16), 256, 0, stream>>>(wob, VT, bo, d_out, x, 256, 512);
}

// Round 5
// 570.729 us; speedup vs baseline: 1.0963x; 1.0963x over previous
//
#include <hip/hip_runtime.h>
#include <hip/hip_bf16.h>

typedef __bf16 bf16;
typedef __bf16 v8bf __attribute__((ext_vector_type(8)));
typedef __bf16 v4bf __attribute__((ext_vector_type(4)));
typedef float  v4f  __attribute__((ext_vector_type(4)));

constexpr int NB   = 16;     // batch
constexpr int CIN  = 256;    // channels
constexpr int NPOS = 2304;   // 48*48 spatial positions
constexpr int CHID = 512;    // hidden
constexpr int CQK  = 96;     // qk channels

// ---- workspace layout (bytes) ----
constexpr size_t OFF_WH   = 0;                               // [1024][256] bf16
constexpr size_t OFF_WQK  = OFF_WH   + 1024ull*256*2;        // [192][256] bf16
constexpr size_t OFF_WOUT = OFF_WQK  + 192ull*256*2;         // [256][512] bf16
constexpr size_t OFF_XT   = OFF_WOUT + 256ull*512*2;         // [B][N][256] bf16
constexpr size_t OFF_ZT   = OFF_XT   + (size_t)NB*NPOS*CIN*2;    // [B][N][192] bf16 (q:0..95, k:96..191)
constexpr size_t OFF_VG   = OFF_ZT   + (size_t)NB*NPOS*192*2;    // [B][1024][N] bf16 (v:0..511, gate:512..1023)
constexpr size_t OFF_VT   = OFF_VG   + (size_t)NB*1024*NPOS*2;   // [B][N][512] bf16

// ---------------------------------------------------------------------------
// cast weights f32 -> bf16
__global__ void cast_weights(const float* __restrict__ wh, const float* __restrict__ wqk,
                             const float* __restrict__ wo,
                             bf16* __restrict__ whb, bf16* __restrict__ wqkb, bf16* __restrict__ wob) {
    int i = blockIdx.x * 256 + threadIdx.x;
    if (i < 1024*256) whb[i]  = (bf16)wh[i];
    if (i < 192*256)  wqkb[i] = (bf16)wqk[i];
    if (i < 256*512)  wob[i]  = (bf16)wo[i];
}

// ---------------------------------------------------------------------------
// x [B][256][N] f32  ->  xT [B][N][256] bf16
__global__ void transpose_cast_x(const float* __restrict__ x, bf16* __restrict__ xT) {
    __shared__ float tile[32][33];
    const int b = blockIdx.z, c0 = blockIdx.y * 32, n0 = blockIdx.x * 32;
    const int tx = threadIdx.x, ty = threadIdx.y;
    const float* xb = x + (size_t)b * CIN * NPOS;
    bf16* xTb = xT + (size_t)b * NPOS * CIN;
    #pragma unroll
    for (int r = ty; r < 32; r += 8) tile[r][tx] = xb[(size_t)(c0 + r) * NPOS + n0 + tx];
    __syncthreads();
    #pragma unroll
    for (int r = ty; r < 32; r += 8) xTb[(size_t)(n0 + r) * CIN + c0 + tx] = (bf16)tile[tx][r];
}

// ---------------------------------------------------------------------------
// Generic bf16 GEMM: D[m][n] = sum_k A[m][k] * Bt[n][k]   (both operands k-contig)
// A: [M][K], Bt: [NB][NPOS][K].  128x128 tile, BK=32, 4 waves (2x2 of 64x64).
// MODE 0: silu(D+bias) -> out bf16 [NB][1024][NPOS]      (vg)
// MODE 1: silu(D+bias) -> out bf16 [NB][NPOS][192] (T)   (zT)
// MODE 2: D+bias+resid -> out f32  [NB][256][NPOS]       (final)
template<int MODE>
__global__ __launch_bounds__(256) void gemm_bt(
    const bf16* __restrict__ A, const bf16* __restrict__ Bt,
    const float* __restrict__ bias, void* __restrict__ outp,
    const float* __restrict__ resid, int M, int K)
{
    __shared__ bf16 sA[128][40];   // +8 pad: breaks 8-way bank conflict on b128 reads
    __shared__ bf16 sB[128][40];
    const int b = blockIdx.z, mt = blockIdx.x, nt = blockIdx.y;
    const int tid = threadIdx.x;
    const int wave = tid >> 6, lane = tid & 63, lo = lane & 15, hi = lane >> 4;
    const int wr = wave >> 1, wc = wave & 1;

    const bf16* Ab = A  + (size_t)mt * 128 * K;
    const bf16* Bb = Bt + ((size_t)b * NPOS + (size_t)nt * 128) * K;

    const int r0 = tid >> 2, koff = (tid & 3) * 8;   // chunk tid   -> row r0
    const int r1 = r0 + 64;                          // chunk tid+256
    const int nk = K >> 5;
    const bool a0ok = (mt * 128 + r0) < M;
    const bool a1ok = (mt * 128 + r1) < M;

    v4f acc[4][4];
    #pragma unroll
    for (int i = 0; i < 4; ++i)
        #pragma unroll
        for (int j = 0; j < 4; ++j) acc[i][j] = (v4f){0.f, 0.f, 0.f, 0.f};

    uint4 ra0 = {0,0,0,0}, ra1 = {0,0,0,0}, rb0, rb1;
    if (a0ok) ra0 = *(const uint4*)(Ab + (size_t)r0 * K + koff);
    if (a1ok) ra1 = *(const uint4*)(Ab + (size_t)r1 * K + koff);
    rb0 = *(const uint4*)(Bb + (size_t)r0 * K + koff);
    rb1 = *(const uint4*)(Bb + (size_t)r1 * K + koff);

    for (int kt = 0; kt < nk; ++kt) {
        __syncthreads();
        *(uint4*)&sA[r0][koff] = ra0;
        *(uint4*)&sA[r1][koff] = ra1;
        *(uint4*)&sB[r0][koff] = rb0;
        *(uint4*)&sB[r1][koff] = rb1;
        __syncthreads();
        if (kt + 1 < nk) {               // prefetch next k-tile; latency hides under MFMA
            const int kb = (kt + 1) * 32 + koff;
            if (a0ok) ra0 = *(const uint4*)(Ab + (size_t)r0 * K + kb);
            if (a1ok) ra1 = *(const uint4*)(Ab + (size_t)r1 * K + kb);
            rb0 = *(const uint4*)(Bb + (size_t)r0 * K + kb);
            rb1 = *(const uint4*)(Bb + (size_t)r1 * K + kb);
        }
        v8bf af[4], bfr[4];
        #pragma unroll
        for (int i = 0; i < 4; ++i) af[i]  = *(const v8bf*)&sA[wr * 64 + i * 16 + lo][hi * 8];
        #pragma unroll
        for (int j = 0; j < 4; ++j) bfr[j] = *(const v8bf*)&sB[wc * 64 + j * 16 + lo][hi * 8];
        #pragma unroll
        for (int i = 0; i < 4; ++i)
            #pragma unroll
            for (int j = 0; j < 4; ++j)
                acc[i][j] = __builtin_amdgcn_mfma_f32_16x16x32_bf16(af[i], bfr[j], acc[i][j], 0, 0, 0);
    }

    // epilogue: D row = (lane>>4)*4 + r, col = lane&15  (verified gfx950 mapping)
    #pragma unroll
    for (int i = 0; i < 4; ++i) {
        const int mg0 = mt * 128 + wr * 64 + i * 16 + hi * 4;
        #pragma unroll
        for (int j = 0; j < 4; ++j) {
            const int ng = nt * 128 + wc * 64 + j * 16 + lo;
            #pragma unroll
            for (int r = 0; r < 4; ++r) {
                const int mg = mg0 + r;
                if (mg >= M) continue;
                float v = acc[i][j][r] + bias[mg];
                if (MODE == 0) {
                    v = v / (1.f + __expf(-v));
                    ((bf16*)outp)[((size_t)b * 1024 + mg) * NPOS + ng] = (bf16)v;
                } else if (MODE == 1) {
                    v = v / (1.f + __expf(-v));
                    ((bf16*)outp)[((size_t)b * NPOS + ng) * 192 + mg] = (bf16)v;
                } else {
                    const size_t idx = ((size_t)b * CIN + mg) * NPOS + ng;
                    ((float*)outp)[idx] = v + resid[idx];
                }
            }
        }
    }
}

// ---------------------------------------------------------------------------
// Fused relu^2 attention, restructured for latency hiding.
// Block: 256 threads (4 waves), covers 64 queries x 256 h-channels (h split in 2).
// Per m-tile of 64: wave w computes S[0:64][w*16:(w+1)*16] (12 MFMA) into the
// *other* S buffer while doing PV (32 MFMA) from the current one -> 1 barrier/iter.
// k prefetched 2 tiles ahead, v 1 tile ahead, ping-pong register sets.
__global__ __launch_bounds__(256) void attn_kernel(
    const bf16* __restrict__ zT,   // [NB][NPOS][192] (q:0..95, k:96..191)
    const bf16* __restrict__ vg,   // [NB][1024][NPOS] (v:0..511, gate:512..1023)
    bf16* __restrict__ VT)         // [NB][NPOS][512]
{
    __shared__ bf16 sS[2][64][76];   // 152B row stride: conflict-free writes, ~2-way reads
    const int b  = blockIdx.y;
    const int n0 = (blockIdx.x >> 1) * 64;
    const int hs = blockIdx.x & 1;
    const int tid = threadIdx.x;
    const int w = tid >> 6, lane = tid & 63, lo = lane & 15, hi = lane >> 4;
    const int h0 = hs * 256 + w * 64;

    const bf16* zTb = zT + (size_t)b * NPOS * 192;
    const bf16* vb  = vg + (size_t)b * 1024 * NPOS;

    // hoisted Q fragments: rows n0+i*16+lo, k = c*32 + hi*8 + e
    v8bf qf[4][3];
    #pragma unroll
    for (int i = 0; i < 4; ++i) {
        const bf16* qp = zTb + (size_t)(n0 + i * 16 + lo) * 192 + hi * 8;
        #pragma unroll
        for (int c = 0; c < 3; ++c) qf[i][c] = *(const v8bf*)(qp + c * 32);
    }

    v4f acc[4][4];
    #pragma unroll
    for (int i = 0; i < 4; ++i)
        #pragma unroll
        for (int j = 0; j < 4; ++j) acc[i][j] = (v4f){0.f, 0.f, 0.f, 0.f};

    const bf16* kbase = zTb + (size_t)(w * 16 + lo) * 192 + 96 + hi * 8;
    const bf16* vbase = vb + (size_t)(h0 + lo) * NPOS + hi * 8;

    auto LOADK = [&](v8bf (&kf)[3], int m0) {
        const bf16* kp = kbase + (size_t)m0 * 192;
        #pragma unroll
        for (int c = 0; c < 3; ++c) kf[c] = *(const v8bf*)(kp + c * 32);
    };
    auto LOADV = [&](v8bf (&av)[4][2], int m0) {
        #pragma unroll
        for (int i2 = 0; i2 < 4; ++i2) {
            const bf16* vp = vbase + (size_t)(i2 * 16) * NPOS + m0;
            av[i2][0] = *(const v8bf*)(vp);
            av[i2][1] = *(const v8bf*)(vp + 32);
        }
    };
    auto COMPS = [&](int p, v8bf (&kf)[3]) {
        v4f s[4];
        #pragma unroll
        for (int i = 0; i < 4; ++i) s[i] = (v4f){0.f, 0.f, 0.f, 0.f};
        #pragma unroll
        for (int c = 0; c < 3; ++c)
            #pragma unroll
            for (int i = 0; i < 4; ++i)
                s[i] = __builtin_amdgcn_mfma_f32_16x16x32_bf16(qf[i][c], kf[c], s[i], 0, 0, 0);
        #pragma unroll
        for (int i = 0; i < 4; ++i)
            #pragma unroll
            for (int r = 0; r < 4; ++r) {
                float t = s[i][r];
                t = t > 0.f ? t * t : 0.f;       // relu^2
                sS[p][i * 16 + hi * 4 + r][w * 16 + lo] = (bf16)t;
            }
    };
    auto PV = [&](int p, v8bf (&av)[4][2]) {
        v8bf bs[4][2];
        #pragma unroll
        for (int j = 0; j < 4; ++j)
            #pragma unroll
            for (int kk = 0; kk < 2; ++kk)
                bs[j][kk] = *(const v8bf*)&sS[p][j * 16 + lo][kk * 32 + hi * 8];
        #pragma unroll
        for (int kk = 0; kk < 2; ++kk)
            #pragma unroll
            for (int i2 = 0; i2 < 4; ++i2)
                #pragma unroll
                for (int j = 0; j < 4; ++j)
                    acc[i2][j] = __builtin_amdgcn_mfma_f32_16x16x32_bf16(av[i2][kk], bs[j][kk], acc[i2][j], 0, 0, 0);
    };

    v8bf kfA[3], kfB[3];
    v8bf avA[4][2], avB[4][2];

    // prologue: S_0 -> buf0; prefetch k(1), v(0)
    LOADK(kfA, 0);
    COMPS(0, kfA);
    LOADK(kfB, 64);
    LOADV(avA, 0);
    __syncthreads();

    for (int mt = 0; mt < 36; mt += 2) {
        // ---- even tile t = mt: consume buf0/avA, build buf1 with kfB ----
        COMPS(1, kfB);                                  // S_{t+1} (t+1 <= 35 always)
        if (mt + 2 < 36) LOADK(kfA, (mt + 2) * 64);     // k for tile t+2
        LOADV(avB, (mt + 1) * 64);                      // v for tile t+1
        PV(0, avA);
        __syncthreads();
        // ---- odd tile t = mt+1: consume buf1/avB, build buf0 with kfA ----
        if (mt + 2 < 36) COMPS(0, kfA);                 // S_{t+2}
        if (mt + 3 < 36) LOADK(kfB, (mt + 3) * 64);     // k for tile t+3
        if (mt + 2 < 36) LOADV(avA, (mt + 2) * 64);     // v for tile t+2
        PV(1, avB);
        __syncthreads();
    }

    // epilogue: V = acc * gate, store VT[b][n][h] as 4 consecutive h (8B stores)
    #pragma unroll
    for (int i2 = 0; i2 < 4; ++i2) {
        const int hb = h0 + i2 * 16 + hi * 4;
        #pragma unroll
        for (int j = 0; j < 4; ++j) {
            const int n = n0 + j * 16 + lo;
            v4bf outv;
            #pragma unroll
            for (int r = 0; r < 4; ++r) {
                const float g = (float)vb[(size_t)(512 + hb + r) * NPOS + n];
                outv[r] = (bf16)(acc[i2][j][r] * g);
            }
            *(v4bf*)&VT[((size_t)b * NPOS + n) * CHID + hb] = outv;
        }
    }
}

// ---------------------------------------------------------------------------
extern "C" void kernel_launch(void* const* d_in, const int* in_sizes, int n_in,
                              void* d_out, int out_size, void* d_ws, size_t ws_size,
                              hipStream_t stream) {
    const float* x   = (const float*)d_in[0];
    const float* wh  = (const float*)d_in[1];
    const float* bh  = (const float*)d_in[2];
    const float* wqk = (const float*)d_in[3];
    const float* bqk = (const float*)d_in[4];
    const float* wo  = (const float*)d_in[5];
    const float* bo  = (const float*)d_in[6];

    char* ws = (char*)d_ws;
    bf16* whb  = (bf16*)(ws + OFF_WH);
    bf16* wqkb = (bf16*)(ws + OFF_WQK);
    bf16* wob  = (bf16*)(ws + OFF_WOUT);
    bf16* xT   = (bf16*)(ws + OFF_XT);
    bf16* zT   = (bf16*)(ws + OFF_ZT);
    bf16* vg   = (bf16*)(ws + OFF_VG);
    bf16* VT   = (bf16*)(ws + OFF_VT);

    cast_weights<<<1024, 256, 0, stream>>>(wh, wqk, wo, whb, wqkb, wob);
    transpose_cast_x<<<dim3(72, 8, 16), dim3(32, 8), 0, stream>>>(x, xT);
    // hid = silu(Wh x + bh): v rows 0..511, gate rows 512..1023
    gemm_bt<0><<<dim3(8, 18, 16), 256, 0, stream>>>(whb, xT, bh, vg, nullptr, 1024, 256);
    // z = silu(Wqk x + bqk), stored transposed: q cols 0..95, k cols 96..191
    gemm_bt<1><<<dim3(2, 18, 16), 256, 0, stream>>>(wqkb, xT, bqk, zT, nullptr, 192, 256);
    // fused relu^2 attention + gate, stores VT[B][N][512]
    // grid.x = n-tile*2 + h-split: consecutive blocks share a batch -> v stays L2-resident
    attn_kernel<<<dim3(72, 16), 256, 0, stream>>>(zT, vg, VT);
    // out = Wout V + bo + x
    gemm_bt<2><<<dim3(2, 18, 16), 256, 0, stream>>>(wob, VT, bo, d_out, x, 256, 512);
}